// Round 8
// baseline (338.164 us; speedup 1.0000x reference)
//
#include <hip/hip_runtime.h>
#include <hip/hip_bf16.h>

typedef unsigned short u16;
typedef unsigned int u32;

constexpr int B_ = 8, T_ = 512, C_ = 1024, H_ = 16, E_ = 64, L_ = 2048;
constexpr int S_ = L_ + T_;  // 2560 merged KV length

typedef __bf16 bf16x8 __attribute__((ext_vector_type(8)));
typedef float f32x4 __attribute__((ext_vector_type(4)));
typedef float f32x16 __attribute__((ext_vector_type(16)));

// 0.125 * log2(e): folds 1/sqrt(E) and the exp->exp2 base change into q
#define QSCALE 0.18033688011112042f

// Km[b,h,s,e] and Vtm[b,h,e,s] are stored PRE-SWIZZLED: within each 128B row
// (8 units of 16B), unit u of row r is stored at u ^ (r & 7). attn stages them
// to LDS linearly via global_load_lds and applies the XOR on the LDS read side.

__device__ inline u16 f2bf(float f) {
  u32 u = __float_as_uint(f);
  u32 r = (u + 0x7fffu + ((u >> 16) & 1u)) >> 16;
  return (u16)r;
}

// packed f32x2 -> bf16x2, hardware RNE single instr
__device__ inline u32 pk2(float a, float b) {
  u32 r;
  asm("v_cvt_pk_bf16_f32 %0, %1, %2" : "=v"(r) : "v"(a), "v"(b));
  return r;
}

// permlane32_swap: a' = concat(a[0:31], b[0:31]); b' = concat(a[32:63], b[32:63])
__device__ inline void pl32swap(u32& a, u32& b) {
  asm("v_permlane32_swap_b32 %0, %1" : "+v"(a), "+v"(b));
}

// async global->LDS, 16B per lane; lds base must be wave-uniform,
// HW writes lds_base + lane*16
__device__ inline void gload_lds16(const u16* g, u16* l) {
  __builtin_amdgcn_global_load_lds(
      (const __attribute__((address_space(1))) u32*)g,
      (__attribute__((address_space(3))) u32*)l, 16, 0, 0);
}

// ---------------- x (f32) -> bf16, 8 elements/thread -------------------------
__global__ __launch_bounds__(256) void convert_f32_bf16(const float* __restrict__ in,
                                                        u16* __restrict__ out) {
  const int i = blockIdx.x * 256 + threadIdx.x;
  const float4 a0 = ((const float4*)in)[i * 2];
  const float4 a1 = ((const float4*)in)[i * 2 + 1];
  uint4 p;
  p.x = pk2(a0.x, a0.y);
  p.y = pk2(a0.z, a0.w);
  p.z = pk2(a1.x, a1.y);
  p.w = pk2(a1.z, a1.w);
  ((uint4*)out)[i] = p;
}

// ------- transpose + downcast: in f32 (R x Ccols) -> out bf16 (Ccols x R) ----
__global__ __launch_bounds__(256) void transpose_f32_bf16(const float* __restrict__ in,
                                                          u16* __restrict__ out,
                                                          int R, int Ccols) {
  __shared__ u16 tile[64][65];
  const int r0 = blockIdx.y * 64;
  const int c0 = blockIdx.x * 64;
  const int tr = threadIdx.x >> 6;  // 0..3
  const int tc = threadIdx.x & 63;
#pragma unroll
  for (int i = 0; i < 16; ++i)
    tile[tr + i * 4][tc] = f2bf(in[(size_t)(r0 + tr + i * 4) * Ccols + c0 + tc]);
  __syncthreads();
#pragma unroll
  for (int i = 0; i < 16; ++i)
    out[(size_t)(c0 + tr + i * 4) * R + r0 + tc] = tile[tc][tr + i * 4];
}

// ---- prep: f32 KV cache -> swizzled bf16 Km[b,h,s,e], Vtm[b,h,e,s] (s<L) ----
__global__ __launch_bounds__(256) void prep_kv(const float* __restrict__ kc,
                                               const float* __restrict__ vc,
                                               u16* __restrict__ Km,
                                               u16* __restrict__ Vtm) {
  __shared__ u16 vt[64 * 72];
  const int s0 = (blockIdx.x & 31) * 64;
  const int bh = blockIdx.x >> 5;
  const int tid = threadIdx.x;
  const int srow = tid >> 2;
  const int eq = (tid & 3) * 16;

  {
    const float* kp = kc + ((size_t)bh * L_ + s0 + srow) * E_ + eq;
    float kv[16];
    *(float4*)(kv + 0) = *(const float4*)(kp + 0);
    *(float4*)(kv + 4) = *(const float4*)(kp + 4);
    *(float4*)(kv + 8) = *(const float4*)(kp + 8);
    *(float4*)(kv + 12) = *(const float4*)(kp + 12);
    uint4 p0, p1;
    p0.x = pk2(kv[0], kv[1]);
    p0.y = pk2(kv[2], kv[3]);
    p0.z = pk2(kv[4], kv[5]);
    p0.w = pk2(kv[6], kv[7]);
    p1.x = pk2(kv[8], kv[9]);
    p1.y = pk2(kv[10], kv[11]);
    p1.z = pk2(kv[12], kv[13]);
    p1.w = pk2(kv[14], kv[15]);
    // swizzled store: 16B unit u at u ^ (s&7)
    const int sx = (srow & 7) << 3;
    u16* kd = Km + ((size_t)bh * S_ + s0 + srow) * E_;
    *(uint4*)(kd + (eq ^ sx)) = p0;
    *(uint4*)(kd + ((eq + 8) ^ sx)) = p1;
  }
  {
    const float* vp = vc + ((size_t)bh * L_ + s0 + srow) * E_ + eq;
    float vv[16];
    *(float4*)(vv + 0) = *(const float4*)(vp + 0);
    *(float4*)(vv + 4) = *(const float4*)(vp + 4);
    *(float4*)(vv + 8) = *(const float4*)(vp + 8);
    *(float4*)(vv + 12) = *(const float4*)(vp + 12);
    uint4 p0, p1;
    p0.x = pk2(vv[0], vv[1]);
    p0.y = pk2(vv[2], vv[3]);
    p0.z = pk2(vv[4], vv[5]);
    p0.w = pk2(vv[6], vv[7]);
    p1.x = pk2(vv[8], vv[9]);
    p1.y = pk2(vv[10], vv[11]);
    p1.z = pk2(vv[12], vv[13]);
    p1.w = pk2(vv[14], vv[15]);
    *(uint4*)(vt + srow * 72 + eq) = p0;
    *(uint4*)(vt + srow * 72 + eq + 8) = p1;
  }
  __syncthreads();
  {
    const int erow = tid >> 2;
    const int sq = (tid & 3) * 16;
    u16 o[16];
#pragma unroll
    for (int j = 0; j < 16; ++j) o[j] = vt[(sq + j) * 72 + erow];
    // swizzled store: within this 64-key chunk, unit u at u ^ (e&7)
    const int ex = (erow & 7) << 3;
    u16* vd = Vtm + ((size_t)bh * E_ + erow) * S_ + s0;
    *(uint4*)(vd + (sq ^ ex)) = *(uint4*)(o + 0);
    *(uint4*)(vd + ((sq + 8) ^ ex)) = *(uint4*)(o + 8);
  }
}

// --------- m97-style GEMM: C[M,N] = A[M,K] @ BT[N,K]^T + bias[n] -------------
// MODE 0: scatter qkv: q (xQSCALE) -> qh[b,h,t,e]; k -> Km[..,L+t,e] swizzled;
//         v -> Vtm[..,e,L+t] swizzled
// MODE 1: f32 row-major store to outf
template <int MODE>
__global__ __launch_bounds__(256) void gemm128(const u16* __restrict__ A,
                                               const u16* __restrict__ BT,
                                               const float* __restrict__ bias,
                                               u16* __restrict__ qh,
                                               u16* __restrict__ Km,
                                               u16* __restrict__ Vtm,
                                               float* __restrict__ outf,
                                               int M, int N, int K) {
  __shared__ __align__(16) u16 As[128 * 32];
  __shared__ __align__(16) u16 Bs[128 * 32];
  const int tid = threadIdx.x;
  const int lane = tid & 63;
  const int w = tid >> 6;
  const int m0 = blockIdx.y * 128;
  const int n0 = blockIdx.x * 128;
  const int wm = (w >> 1) * 64;
  const int wn = (w & 1) * 64;
  const int fm = lane & 15;
  const int fk = (lane >> 4) * 8;

  const int srow = w * 16 + (lane >> 2);
  const int scol = (lane & 3) * 8;
  const u16* Ag = A + (size_t)(m0 + srow) * K + scol;
  const u16* Bg = BT + (size_t)(n0 + srow) * K + scol;
  u16* AsU = As + w * 512;
  u16* BsU = Bs + w * 512;

  f32x4 acc[4][4];
#pragma unroll
  for (int i = 0; i < 4; ++i)
#pragma unroll
    for (int j = 0; j < 4; ++j) acc[i][j] = f32x4{0.f, 0.f, 0.f, 0.f};

  for (int k0 = 0; k0 < K; k0 += 32) {
    gload_lds16(Ag, AsU);
    gload_lds16(Ag + (size_t)64 * K, AsU + 2048);
    gload_lds16(Bg, BsU);
    gload_lds16(Bg + (size_t)64 * K, BsU + 2048);
    Ag += 32;
    Bg += 32;
    __syncthreads();
    bf16x8 af[4], bf[4];
#pragma unroll
    for (int i = 0; i < 4; ++i)
      af[i] = *(const bf16x8*)(As + (wm + i * 16 + fm) * 32 + fk);
#pragma unroll
    for (int j = 0; j < 4; ++j)
      bf[j] = *(const bf16x8*)(Bs + (wn + j * 16 + fm) * 32 + fk);
#pragma unroll
    for (int i = 0; i < 4; ++i)
#pragma unroll
      for (int j = 0; j < 4; ++j)
        acc[i][j] = __builtin_amdgcn_mfma_f32_16x16x32_bf16(af[i], bf[j], acc[i][j], 0, 0, 0);
    __syncthreads();
  }

  const int rbase = (lane >> 4) * 4;
  const int cbase = lane & 15;
#pragma unroll
  for (int i = 0; i < 4; ++i)
#pragma unroll
    for (int j = 0; j < 4; ++j) {
      const int n = n0 + wn + j * 16 + cbase;
      const float bv = bias[n];
#pragma unroll
      for (int r = 0; r < 4; ++r) {
        const int m = m0 + wm + i * 16 + rbase + r;
        const float v = acc[i][j][r] + bv;
        if (MODE == 0) {
          const int seg = n >> 10;  // 0:q 1:k 2:v
          const int c = n & 1023;
          const int e = c & 63;
          const int bhh = ((m >> 9) * H_) + (c >> 6);
          const int t = m & 511;
          if (seg == 0)
            qh[((size_t)bhh * T_ + t) * E_ + e] = f2bf(v * QSCALE);
          else if (seg == 1)  // swizzle: e ^ ((s&7)<<3), s = L+t, L%8==0
            Km[((size_t)bhh * S_ + L_ + t) * E_ + (e ^ ((t & 7) << 3))] = f2bf(v);
          else                // swizzle: keypos ^ ((e&7)<<3) (bits 3-5 = unit)
            Vtm[((size_t)bhh * E_ + e) * S_ + ((L_ + t) ^ ((e & 7) << 3))] = f2bf(v);
        } else {
          outf[(size_t)m * N + n] = v;
        }
      }
    }
}

// ----- MFMA flash attention v9: contiguous key-halves, 4 waves/SIMD ----------
// 512 threads = 4 q-waves x 2 key-sides. Side 0: chunks [0,m); side 1: [m,
// nchunk) (nchunk even => m=nchunk/2, balanced; every wave computes every
// round of ITS stream -- no v6 idling). Each side is an independent v8
// pipeline (own gload_lds staging, own counted vmcnt), sharing only the
// block barrier. Grid 512 -> 2 blocks/CU x 8 waves = 4 waves/SIMD.
// LDS: per side K 3-buf + V 2-buf = 80KB exactly (V needed 1 round ahead
// only; V-then-K issue order lets vmcnt(2) retain just the K prefetch
// across the barrier). (Y,l) are pure sums -> cross-side LDS reduction.
__global__ __launch_bounds__(512, 4) void attn_v9(const u16* __restrict__ qh,
                                                  const u16* __restrict__ Km,
                                                  const u16* __restrict__ Vtm,
                                                  u16* __restrict__ y2) {
  __shared__ __align__(16) u16 Ksf[6 * 4096];   // [side*3 + buf][64x64]
  __shared__ __align__(16) u16 Vtsf[4 * 4096];  // [side*2 + buf][64x64]

  const int tid = threadIdx.x;
  const int lane = tid & 63;
  const int w = tid >> 6;    // 0..7
  const int wq = w & 3;      // q-tile wave within side
  const int side = w >> 2;   // key half
  const int bh = blockIdx.x & 127;
  const int qt = blockIdx.x >> 7;
  const int h = bh & (H_ - 1);
  const int b = bh >> 4;
  const int t0 = qt * 128;

  const int ln = lane & 31;
  const int hi = lane >> 5;
  const int swz = ln & 7;

  // ---- Q fragments (B-operand): lane holds Q[q=ln][e = et*16 + hi*8 + j]
  const u16* qbase = qh + ((size_t)bh * T_ + t0 + wq * 32 + ln) * E_;
  bf16x8 qf[4];
#pragma unroll
  for (int et = 0; et < 4; ++et)
    qf[et] = *(const bf16x8*)(qbase + et * 16 + hi * 8);

  // ---- staging: within its side, wave wq stages rows [wq*16, wq*16+16)
  const int l8 = lane >> 3;
  const int u8 = lane & 7;
  const u16* kgl = Km + ((size_t)bh * S_ + wq * 16 + l8) * E_ + u8 * 8;
  const u16* vgl = Vtm + ((size_t)bh * E_ + wq * 16 + l8) * S_ + u8 * 8;
  const int kdst = wq * 1024;  // u16 units; +512 = +8 rows

  const int qmin_w = L_ + t0 + wq * 32;
  const int qpos = qmin_w + ln;
  const int nchunk = (L_ + t0 + 128) >> 6;  // 34/36/38/40: always even
  const int m = nchunk >> 1;
  const int c0 = side ? m : 0;  // this side's first chunk

#define STAGE_K(rr, kb)                                                        \
  do {                                                                         \
    gload_lds16(kgl + (size_t)(c0 + (rr)) * 64 * E_,                           \
                Ksf + (side * 3 + (kb)) * 4096 + kdst);                        \
    gload_lds16(kgl + ((size_t)(c0 + (rr)) * 64 + 8) * E_,                     \
                Ksf + (side * 3 + (kb)) * 4096 + kdst + 512);                  \
  } while (0)
#define STAGE_V(rr, vb)                                                        \
  do {                                                                         \
    gload_lds16(vgl + (c0 + (rr)) * 64,                                        \
                Vtsf + (side * 2 + (vb)) * 4096 + kdst);                       \
    gload_lds16(vgl + (size_t)8 * S_ + (c0 + (rr)) * 64,                       \
                Vtsf + (side * 2 + (vb)) * 4096 + kdst + 512);                 \
  } while (0)

  f32x16 Yt[2], lacc, zero16;
#pragma unroll
  for (int i = 0; i < 16; ++i) {
    Yt[0][i] = 0.f;
    Yt[1][i] = 0.f;
    lacc[i] = 0.f;
    zero16[i] = 0.f;
  }

  const bf16x8 ones = {(__bf16)1.f, (__bf16)1.f, (__bf16)1.f, (__bf16)1.f,
                       (__bf16)1.f, (__bf16)1.f, (__bf16)1.f, (__bf16)1.f};

  // ---- prologue: K(0), V(0), K(1) in flight; wait K0+V0, keep K1 in flight
  STAGE_K(0, 0);
  STAGE_V(0, 0);
  STAGE_K(1, 1);
  asm volatile("s_waitcnt vmcnt(2)" ::: "memory");
  __builtin_amdgcn_s_barrier();

  int i0 = 0, i1 = 1, i2 = 2;
  for (int r = 0; r < m; ++r) {
    // issue early (T14): V one ahead, K two ahead (V first, K last, so the
    // end-of-round vmcnt(2) retains only K's prefetch across the barrier)
    if (r + 1 < m) STAGE_V(r + 1, (r + 1) & 1);
    if (r + 2 < m) STAGE_K(r + 2, i2);

    const int c = c0 + r;
    if ((c << 6) <= qmin_w + 31) {  // not beyond this wave's causal bound
      const int sbase = c << 6;
      const u16* ks = Ksf + (side * 3 + i0) * 4096;
      const u16* vs = Vtsf + (side * 2 + (r & 1)) * 4096;
      bf16x8 pa[4];
#pragma unroll
      for (int kb = 0; kb < 2; ++kb) {
        // ---- S^T = K.Q^T (D: row=key_local, col=q_local), C-in = zero16
        f32x16 s;
#pragma unroll
        for (int et = 0; et < 4; ++et) {
          const bf16x8 kf = *(const bf16x8*)(
              ks + (kb * 32 + ln) * 64 + (((et * 2 + hi) ^ swz) * 8));
          s = __builtin_amdgcn_mfma_f32_32x32x16_bf16(kf, qf[et],
                                                      et == 0 ? zero16 : s, 0, 0, 0);
        }

        // ---- causal mask (straddling chunks only; side 0 never straddles)
        if (sbase + 63 > qmin_w) {
          const int mb = sbase + kb * 32 + hi * 4;
#pragma unroll
          for (int rr = 0; rr < 16; ++rr) {
            const int keypos = mb + (rr & 3) + 8 * (rr >> 2);
            if (keypos > qpos) s[rr] = -1e30f;
          }
        }

        // ---- p = exp2(s) (no max tracking: scores bounded)
#pragma unroll
        for (int rr = 0; rr < 16; ++rr) s[rr] = exp2f(s[rr]);

        // ---- pack to bf16 + permlane32_swap -> PV A-fragments (T12)
#pragma unroll
        for (int t = 0; t < 2; ++t) {
          u32 x0 = pk2(s[8 * t + 0], s[8 * t + 1]);
          u32 y0 = pk2(s[8 * t + 4], s[8 * t + 5]);
          u32 x1 = pk2(s[8 * t + 2], s[8 * t + 3]);
          u32 y1 = pk2(s[8 * t + 6], s[8 * t + 7]);
          pl32swap(x0, y0);
          pl32swap(x1, y1);
          union { u32 u[4]; bf16x8 v; } pu;
          pu.u[0] = x0;
          pu.u[1] = x1;
          pu.u[2] = y0;
          pu.u[3] = y1;
          pa[kb * 2 + t] = pu.v;
        }
      }

      // ---- l += P @ 1 (ones-MFMA: D col=q, all rows equal)
#pragma unroll
      for (int t = 0; t < 4; ++t)
        lacc = __builtin_amdgcn_mfma_f32_32x32x16_bf16(ones, pa[t], lacc, 0, 0, 0);

      // ---- Y^T += V^T.P^T (D: row=e_local, col=q_local)
#pragma unroll
      for (int eb = 0; eb < 2; ++eb)
#pragma unroll
        for (int t = 0; t < 4; ++t) {
          const bf16x8 vf = *(const bf16x8*)(
              vs + (eb * 32 + ln) * 64 + (((t * 2 + hi) ^ swz) * 8));
          Yt[eb] = __builtin_amdgcn_mfma_f32_32x32x16_bf16(vf, pa[t], Yt[eb], 0, 0, 0);
        }
    }

    // ---- counted wait: next round needs K(r+1),V(r+1) resident; K(r+2)'s
    // 2 loads stay in flight across the barrier (T4)
    if (r + 2 < m)
      asm volatile("s_waitcnt vmcnt(2)" ::: "memory");
    else
      asm volatile("s_waitcnt vmcnt(0)" ::: "memory");
    __builtin_amdgcn_s_barrier();

    const int tmp = i0;
    i0 = i1;
    i1 = i2;
    i2 = tmp;
  }
#undef STAGE_K
#undef STAGE_V

  // ---- cross-side reduction: (Y,l) are pure sums (reuse Ksf, 33.8KB)
  float* red = (float*)Ksf;
  if (side == 1) {
    float* rp = red + ((size_t)(wq * 64 + lane)) * 33;
#pragma unroll
    for (int i = 0; i < 16; ++i) rp[i] = Yt[0][i];
#pragma unroll
    for (int i = 0; i < 16; ++i) rp[16 + i] = Yt[1][i];
    rp[32] = lacc[0];
  }
  __syncthreads();
  if (side == 0) {
    const float* rp = red + ((size_t)(wq * 64 + lane)) * 33;
#pragma unroll
    for (int i = 0; i < 16; ++i) Yt[0][i] += rp[i];
#pragma unroll
    for (int i = 0; i < 16; ++i) Yt[1][i] += rp[16 + i];
    const float rl = 1.f / (lacc[0] + rp[32]);

    // ---- epilogue: lane holds q = ln; e = 32*eb + 8*(r>>2) + 4*hi + (r&3)
    const int t_out = t0 + wq * 32 + ln;
    u16* yp = y2 + ((size_t)b * T_ + t_out) * C_ + h * E_ + hi * 4;
#pragma unroll
    for (int eb = 0; eb < 2; ++eb)
#pragma unroll
      for (int g = 0; g < 4; ++g) {
        uint2 st;
        st.x = pk2(Yt[eb][4 * g + 0] * rl, Yt[eb][4 * g + 1] * rl);
        st.y = pk2(Yt[eb][4 * g + 2] * rl, Yt[eb][4 * g + 3] * rl);
        *(uint2*)(yp + eb * 32 + g * 8) = st;
      }
  }
}

// ---------------- launch -----------------------------------------------------
extern "C" void kernel_launch(void* const* d_in, const int* in_sizes, int n_in,
                              void* d_out, int out_size, void* d_ws, size_t ws_size,
                              hipStream_t stream) {
  const float* x = (const float*)d_in[0];
  const float* kc = (const float*)d_in[1];
  const float* vc = (const float*)d_in[2];
  const float* Wqkv = (const float*)d_in[3];
  const float* bqkv = (const float*)d_in[4];
  const float* Wproj = (const float*)d_in[5];
  const float* bproj = (const float*)d_in[6];
  float* out = (float*)d_out;

  u16* qh = (u16*)d_ws;                  // 4194304
  u16* y2 = qh + 4194304;                // 4194304
  u16* xb = y2 + 4194304;                // 4194304
  u16* WqT = xb + 4194304;               // 3145728
  u16* WpT = WqT + 3145728;              // 1048576
  u16* Km = WpT + 1048576;               // 20971520 (swizzled layout)
  u16* Vtm = Km + 20971520;              // 20971520 (swizzled layout)

  convert_f32_bf16<<<dim3(2048), 256, 0, stream>>>(x, xb);
  transpose_f32_bf16<<<dim3(48, 16), 256, 0, stream>>>(Wqkv, WqT, 1024, 3072);
  transpose_f32_bf16<<<dim3(16, 16), 256, 0, stream>>>(Wproj, WpT, 1024, 1024);
  prep_kv<<<dim3(128 * 32), 256, 0, stream>>>(kc, vc, Km, Vtm);

  // qkv = x @ Wqkv + bqkv -> qh (xQSCALE), Km[:, L:], Vtm[:, :, L:] (swizzled)
  gemm128<0><<<dim3(24, 32), 256, 0, stream>>>(xb, WqT, bqkv, qh, Km, Vtm, nullptr,
                                               4096, 3072, 1024);

  attn_v9<<<dim3(512), 512, 0, stream>>>(qh, Km, Vtm, y2);

  // out = y @ Wproj + bproj (f32 out)
  gemm128<1><<<dim3(8, 32), 256, 0, stream>>>(y2, WpT, bproj, nullptr, nullptr,
                                              nullptr, out, 4096, 1024, 1024);
}

// Round 9
// 326.252 us; speedup vs baseline: 1.0365x; 1.0365x over previous
//
#include <hip/hip_runtime.h>
#include <hip/hip_bf16.h>

typedef unsigned short u16;
typedef unsigned int u32;

constexpr int B_ = 8, T_ = 512, C_ = 1024, H_ = 16, E_ = 64, L_ = 2048;
constexpr int S_ = L_ + T_;  // 2560 merged KV length

typedef __bf16 bf16x8 __attribute__((ext_vector_type(8)));
typedef float f32x4 __attribute__((ext_vector_type(4)));
typedef float f32x16 __attribute__((ext_vector_type(16)));

// 0.125 * log2(e): folds 1/sqrt(E) and the exp->exp2 base change into q
#define QSCALE 0.18033688011112042f

// Km[b,h,s,e] and Vtm[b,h,e,s] are stored PRE-SWIZZLED: within each 128B row
// (8 units of 16B), unit u of row r is stored at u ^ (r & 7). attn stages them
// to LDS linearly via global_load_lds and applies the XOR on the LDS read side.

__device__ inline u16 f2bf(float f) {
  u32 u = __float_as_uint(f);
  u32 r = (u + 0x7fffu + ((u >> 16) & 1u)) >> 16;
  return (u16)r;
}

// packed f32x2 -> bf16x2, hardware RNE single instr
__device__ inline u32 pk2(float a, float b) {
  u32 r;
  asm("v_cvt_pk_bf16_f32 %0, %1, %2" : "=v"(r) : "v"(a), "v"(b));
  return r;
}

// permlane32_swap: a' = concat(a[0:31], b[0:31]); b' = concat(a[32:63], b[32:63])
__device__ inline void pl32swap(u32& a, u32& b) {
  asm("v_permlane32_swap_b32 %0, %1" : "+v"(a), "+v"(b));
}

// async global->LDS, 16B per lane; lds base must be wave-uniform,
// HW writes lds_base + lane*16
__device__ inline void gload_lds16(const u16* g, u16* l) {
  __builtin_amdgcn_global_load_lds(
      (const __attribute__((address_space(1))) u32*)g,
      (__attribute__((address_space(3))) u32*)l, 16, 0, 0);
}

// ---------------- x (f32) -> bf16, 8 elements/thread -------------------------
__global__ __launch_bounds__(256) void convert_f32_bf16(const float* __restrict__ in,
                                                        u16* __restrict__ out) {
  const int i = blockIdx.x * 256 + threadIdx.x;
  const float4 a0 = ((const float4*)in)[i * 2];
  const float4 a1 = ((const float4*)in)[i * 2 + 1];
  uint4 p;
  p.x = pk2(a0.x, a0.y);
  p.y = pk2(a0.z, a0.w);
  p.z = pk2(a1.x, a1.y);
  p.w = pk2(a1.z, a1.w);
  ((uint4*)out)[i] = p;
}

// ------- transpose + downcast: in f32 (R x Ccols) -> out bf16 (Ccols x R) ----
__global__ __launch_bounds__(256) void transpose_f32_bf16(const float* __restrict__ in,
                                                          u16* __restrict__ out,
                                                          int R, int Ccols) {
  __shared__ u16 tile[64][65];
  const int r0 = blockIdx.y * 64;
  const int c0 = blockIdx.x * 64;
  const int tr = threadIdx.x >> 6;  // 0..3
  const int tc = threadIdx.x & 63;
#pragma unroll
  for (int i = 0; i < 16; ++i)
    tile[tr + i * 4][tc] = f2bf(in[(size_t)(r0 + tr + i * 4) * Ccols + c0 + tc]);
  __syncthreads();
#pragma unroll
  for (int i = 0; i < 16; ++i)
    out[(size_t)(c0 + tr + i * 4) * R + r0 + tc] = tile[tc][tr + i * 4];
}

// ---- prep: f32 KV cache -> swizzled bf16 Km[b,h,s,e], Vtm[b,h,e,s] (s<L) ----
__global__ __launch_bounds__(256) void prep_kv(const float* __restrict__ kc,
                                               const float* __restrict__ vc,
                                               u16* __restrict__ Km,
                                               u16* __restrict__ Vtm) {
  __shared__ u16 vt[64 * 72];
  const int s0 = (blockIdx.x & 31) * 64;
  const int bh = blockIdx.x >> 5;
  const int tid = threadIdx.x;
  const int srow = tid >> 2;
  const int eq = (tid & 3) * 16;

  {
    const float* kp = kc + ((size_t)bh * L_ + s0 + srow) * E_ + eq;
    float kv[16];
    *(float4*)(kv + 0) = *(const float4*)(kp + 0);
    *(float4*)(kv + 4) = *(const float4*)(kp + 4);
    *(float4*)(kv + 8) = *(const float4*)(kp + 8);
    *(float4*)(kv + 12) = *(const float4*)(kp + 12);
    uint4 p0, p1;
    p0.x = pk2(kv[0], kv[1]);
    p0.y = pk2(kv[2], kv[3]);
    p0.z = pk2(kv[4], kv[5]);
    p0.w = pk2(kv[6], kv[7]);
    p1.x = pk2(kv[8], kv[9]);
    p1.y = pk2(kv[10], kv[11]);
    p1.z = pk2(kv[12], kv[13]);
    p1.w = pk2(kv[14], kv[15]);
    // swizzled store: 16B unit u at u ^ (s&7)
    const int sx = (srow & 7) << 3;
    u16* kd = Km + ((size_t)bh * S_ + s0 + srow) * E_;
    *(uint4*)(kd + (eq ^ sx)) = p0;
    *(uint4*)(kd + ((eq + 8) ^ sx)) = p1;
  }
  {
    const float* vp = vc + ((size_t)bh * L_ + s0 + srow) * E_ + eq;
    float vv[16];
    *(float4*)(vv + 0) = *(const float4*)(vp + 0);
    *(float4*)(vv + 4) = *(const float4*)(vp + 4);
    *(float4*)(vv + 8) = *(const float4*)(vp + 8);
    *(float4*)(vv + 12) = *(const float4*)(vp + 12);
    uint4 p0, p1;
    p0.x = pk2(vv[0], vv[1]);
    p0.y = pk2(vv[2], vv[3]);
    p0.z = pk2(vv[4], vv[5]);
    p0.w = pk2(vv[6], vv[7]);
    p1.x = pk2(vv[8], vv[9]);
    p1.y = pk2(vv[10], vv[11]);
    p1.z = pk2(vv[12], vv[13]);
    p1.w = pk2(vv[14], vv[15]);
    *(uint4*)(vt + srow * 72 + eq) = p0;
    *(uint4*)(vt + srow * 72 + eq + 8) = p1;
  }
  __syncthreads();
  {
    const int erow = tid >> 2;
    const int sq = (tid & 3) * 16;
    u16 o[16];
#pragma unroll
    for (int j = 0; j < 16; ++j) o[j] = vt[(sq + j) * 72 + erow];
    // swizzled store: within this 64-key chunk, unit u at u ^ (e&7)
    const int ex = (erow & 7) << 3;
    u16* vd = Vtm + ((size_t)bh * E_ + erow) * S_ + s0;
    *(uint4*)(vd + (sq ^ ex)) = *(uint4*)(o + 0);
    *(uint4*)(vd + ((sq + 8) ^ ex)) = *(uint4*)(o + 8);
  }
}

// --------- m97-style GEMM: C[M,N] = A[M,K] @ BT[N,K]^T + bias[n] -------------
// 128x128 tile, BK=32, global_load_lds staging, 4 waves each 64x64.
// MODE 0: scatter qkv: q (xQSCALE) -> qh[b,h,t,e]; k -> Km[..,L+t,e] swizzled;
//         v -> Vtm[..,e,L+t] swizzled
// MODE 1: f32 row-major store to outf
template <int MODE>
__global__ __launch_bounds__(256) void gemm128(const u16* __restrict__ A,
                                               const u16* __restrict__ BT,
                                               const float* __restrict__ bias,
                                               u16* __restrict__ qh,
                                               u16* __restrict__ Km,
                                               u16* __restrict__ Vtm,
                                               float* __restrict__ outf,
                                               int M, int N, int K) {
  __shared__ __align__(16) u16 As[128 * 32];
  __shared__ __align__(16) u16 Bs[128 * 32];
  const int tid = threadIdx.x;
  const int lane = tid & 63;
  const int w = tid >> 6;
  const int m0 = blockIdx.y * 128;
  const int n0 = blockIdx.x * 128;
  const int wm = (w >> 1) * 64;
  const int wn = (w & 1) * 64;
  const int fm = lane & 15;
  const int fk = (lane >> 4) * 8;

  const int srow = w * 16 + (lane >> 2);
  const int scol = (lane & 3) * 8;
  const u16* Ag = A + (size_t)(m0 + srow) * K + scol;
  const u16* Bg = BT + (size_t)(n0 + srow) * K + scol;
  u16* AsU = As + w * 512;
  u16* BsU = Bs + w * 512;

  f32x4 acc[4][4];
#pragma unroll
  for (int i = 0; i < 4; ++i)
#pragma unroll
    for (int j = 0; j < 4; ++j) acc[i][j] = f32x4{0.f, 0.f, 0.f, 0.f};

  for (int k0 = 0; k0 < K; k0 += 32) {
    gload_lds16(Ag, AsU);
    gload_lds16(Ag + (size_t)64 * K, AsU + 2048);
    gload_lds16(Bg, BsU);
    gload_lds16(Bg + (size_t)64 * K, BsU + 2048);
    Ag += 32;
    Bg += 32;
    __syncthreads();
    bf16x8 af[4], bf[4];
#pragma unroll
    for (int i = 0; i < 4; ++i)
      af[i] = *(const bf16x8*)(As + (wm + i * 16 + fm) * 32 + fk);
#pragma unroll
    for (int j = 0; j < 4; ++j)
      bf[j] = *(const bf16x8*)(Bs + (wn + j * 16 + fm) * 32 + fk);
#pragma unroll
    for (int i = 0; i < 4; ++i)
#pragma unroll
      for (int j = 0; j < 4; ++j)
        acc[i][j] = __builtin_amdgcn_mfma_f32_16x16x32_bf16(af[i], bf[j], acc[i][j], 0, 0, 0);
    __syncthreads();
  }

  const int rbase = (lane >> 4) * 4;
  const int cbase = lane & 15;
#pragma unroll
  for (int i = 0; i < 4; ++i)
#pragma unroll
    for (int j = 0; j < 4; ++j) {
      const int n = n0 + wn + j * 16 + cbase;
      const float bv = bias[n];
#pragma unroll
      for (int r = 0; r < 4; ++r) {
        const int m = m0 + wm + i * 16 + rbase + r;
        const float v = acc[i][j][r] + bv;
        if (MODE == 0) {
          const int seg = n >> 10;  // 0:q 1:k 2:v
          const int c = n & 1023;
          const int e = c & 63;
          const int bhh = ((m >> 9) * H_) + (c >> 6);
          const int t = m & 511;
          if (seg == 0)
            qh[((size_t)bhh * T_ + t) * E_ + e] = f2bf(v * QSCALE);
          else if (seg == 1)  // swizzle: e ^ ((s&7)<<3), s = L+t, L%8==0
            Km[((size_t)bhh * S_ + L_ + t) * E_ + (e ^ ((t & 7) << 3))] = f2bf(v);
          else                // swizzle: keypos ^ ((e&7)<<3) (bits 3-5 = unit)
            Vtm[((size_t)bhh * E_ + e) * S_ + ((L_ + t) ^ ((e & 7) << 3))] = f2bf(v);
        } else {
          outf[(size_t)m * N + n] = v;
        }
      }
    }
}

// --------- gemm64: C[M,N] = A[M,K] @ BT[N,K]^T + bias, f32 out ---------------
// 64x64 tile, 4 waves each 32x32. For the small proj GEMM: grid 16x64 = 1024
// blocks = 4 blocks/CU = 4 waves/SIMD (the 128x128 version ran 1 block/CU =
// 1 wave/SIMD, latency-starved). Same BK=32 accumulation order -> bit-identical.
__global__ __launch_bounds__(256) void gemm64(const u16* __restrict__ A,
                                              const u16* __restrict__ BT,
                                              const float* __restrict__ bias,
                                              float* __restrict__ outf,
                                              int M, int N, int K) {
  __shared__ __align__(16) u16 As[64 * 32];
  __shared__ __align__(16) u16 Bs[64 * 32];
  const int tid = threadIdx.x;
  const int lane = tid & 63;
  const int w = tid >> 6;
  const int m0 = blockIdx.y * 64;
  const int n0 = blockIdx.x * 64;
  const int wm = (w >> 1) * 32;
  const int wn = (w & 1) * 32;
  const int fm = lane & 15;
  const int fk = (lane >> 4) * 8;

  // staging: wave w stages rows [w*16, w*16+16) of the A and B tiles
  const int srow = w * 16 + (lane >> 2);
  const int scol = (lane & 3) * 8;
  const u16* Ag = A + (size_t)(m0 + srow) * K + scol;
  const u16* Bg = BT + (size_t)(n0 + srow) * K + scol;
  u16* AsU = As + w * 512;
  u16* BsU = Bs + w * 512;

  f32x4 acc[2][2];
#pragma unroll
  for (int i = 0; i < 2; ++i)
#pragma unroll
    for (int j = 0; j < 2; ++j) acc[i][j] = f32x4{0.f, 0.f, 0.f, 0.f};

  for (int k0 = 0; k0 < K; k0 += 32) {
    gload_lds16(Ag, AsU);
    gload_lds16(Bg, BsU);
    Ag += 32;
    Bg += 32;
    __syncthreads();
    bf16x8 af[2], bf[2];
#pragma unroll
    for (int i = 0; i < 2; ++i)
      af[i] = *(const bf16x8*)(As + (wm + i * 16 + fm) * 32 + fk);
#pragma unroll
    for (int j = 0; j < 2; ++j)
      bf[j] = *(const bf16x8*)(Bs + (wn + j * 16 + fm) * 32 + fk);
#pragma unroll
    for (int i = 0; i < 2; ++i)
#pragma unroll
      for (int j = 0; j < 2; ++j)
        acc[i][j] = __builtin_amdgcn_mfma_f32_16x16x32_bf16(af[i], bf[j], acc[i][j], 0, 0, 0);
    __syncthreads();
  }

  const int rbase = (lane >> 4) * 4;
  const int cbase = lane & 15;
#pragma unroll
  for (int i = 0; i < 2; ++i)
#pragma unroll
    for (int j = 0; j < 2; ++j) {
      const int n = n0 + wn + j * 16 + cbase;
      const float bv = bias[n];
#pragma unroll
      for (int r = 0; r < 4; ++r) {
        const int m = m0 + wm + i * 16 + rbase + r;
        outf[(size_t)m * N + n] = acc[i][j][r] + bv;
      }
    }
}

// ----- MFMA flash attention v10: v8 + statically-unrolled 3-phase rotation ---
// v8 measured 75us (best); v9's 2x occupancy changed nothing (per-wave-bound).
// Here the 3-buffer rotation indices become compile-time constants (chunk c
// <-> buffer c%3), so all 16 ds_read addresses and STAGE destinations fold to
// base + offset:imm -- removing the per-chunk rotation/addressing VALU.
__global__ __launch_bounds__(256, 2) void attn_v10(const u16* __restrict__ qh,
                                                   const u16* __restrict__ Km,
                                                   const u16* __restrict__ Vtm,
                                                   u16* __restrict__ y2) {
  __shared__ __align__(16) u16 Ksf[3 * 4096];
  __shared__ __align__(16) u16 Vtsf[3 * 4096];

  const int tid = threadIdx.x;
  const int lane = tid & 63;
  const int w = tid >> 6;
  const int bh = blockIdx.x & 127;  // same-bh blocks 128 apart
  const int qt = blockIdx.x >> 7;
  const int h = bh & (H_ - 1);
  const int b = bh >> 4;
  const int t0 = qt * 128;

  const int ln = lane & 31;
  const int hi = lane >> 5;
  const int swz = ln & 7;

  // ---- Q fragments (B-operand): lane holds Q[q=ln][e = et*16 + hi*8 + j]
  const u16* qbase = qh + ((size_t)bh * T_ + t0 + w * 32 + ln) * E_;
  bf16x8 qf[4];
#pragma unroll
  for (int et = 0; et < 4; ++et)
    qf[et] = *(const bf16x8*)(qbase + et * 16 + hi * 8);

  // ---- staging: wave w stages rows [w*16, w*16+16) of each 64-row tile.
  const int l8 = lane >> 3;
  const int u8 = lane & 7;
  const u16* kgl = Km + ((size_t)bh * S_ + w * 16 + l8) * E_ + u8 * 8;
  const u16* vgl = Vtm + ((size_t)bh * E_ + w * 16 + l8) * S_ + u8 * 8;
  const int kdst = w * 1024;  // u16 units; +512 = +8 rows

#define STAGE(cc, bi)                                                       \
  do {                                                                      \
    gload_lds16(kgl + (size_t)(cc) * 64 * E_, Ksf + (bi) * 4096 + kdst);    \
    gload_lds16(kgl + ((size_t)(cc) * 64 + 8) * E_,                         \
                Ksf + (bi) * 4096 + kdst + 512);                            \
    gload_lds16(vgl + (cc) * 64, Vtsf + (bi) * 4096 + kdst);                \
    gload_lds16(vgl + (size_t)8 * S_ + (cc) * 64,                           \
                Vtsf + (bi) * 4096 + kdst + 512);                           \
  } while (0)

  f32x16 Yt[2], lacc, zero16;
#pragma unroll
  for (int i = 0; i < 16; ++i) {
    Yt[0][i] = 0.f;
    Yt[1][i] = 0.f;
    lacc[i] = 0.f;
    zero16[i] = 0.f;
  }

  const bf16x8 ones = {(__bf16)1.f, (__bf16)1.f, (__bf16)1.f, (__bf16)1.f,
                       (__bf16)1.f, (__bf16)1.f, (__bf16)1.f, (__bf16)1.f};

  const int qmin_w = L_ + t0 + w * 32;
  const int qpos = qmin_w + ln;
  const int nchunk = (L_ + t0 + 128) >> 6;  // 34..40

// compute chunk cc from static buffer BI
#define COMPUTE(cc, BI)                                                        \
  do {                                                                         \
    if (((cc) << 6) <= qmin_w + 31) {                                          \
      const int sbase = (cc) << 6;                                             \
      const u16* ks = Ksf + (BI) * 4096;                                       \
      const u16* vs = Vtsf + (BI) * 4096;                                      \
      bf16x8 pa[4];                                                            \
      _Pragma("unroll") for (int kb = 0; kb < 2; ++kb) {                       \
        f32x16 s;                                                              \
        _Pragma("unroll") for (int et = 0; et < 4; ++et) {                     \
          const bf16x8 kf = *(const bf16x8*)(                                  \
              ks + (kb * 32 + ln) * 64 + (((et * 2 + hi) ^ swz) * 8));         \
          s = __builtin_amdgcn_mfma_f32_32x32x16_bf16(kf, qf[et],              \
                                                      et == 0 ? zero16 : s,    \
                                                      0, 0, 0);                \
        }                                                                      \
        if (sbase + 63 > qmin_w) {                                             \
          const int mb = sbase + kb * 32 + hi * 4;                             \
          _Pragma("unroll") for (int rr = 0; rr < 16; ++rr) {                  \
            const int keypos = mb + (rr & 3) + 8 * (rr >> 2);                  \
            if (keypos > qpos) s[rr] = -1e30f;                                 \
          }                                                                    \
        }                                                                      \
        _Pragma("unroll") for (int rr = 0; rr < 16; ++rr) s[rr] = exp2f(s[rr]);\
        _Pragma("unroll") for (int t = 0; t < 2; ++t) {                        \
          u32 x0 = pk2(s[8 * t + 0], s[8 * t + 1]);                            \
          u32 y0 = pk2(s[8 * t + 4], s[8 * t + 5]);                            \
          u32 x1 = pk2(s[8 * t + 2], s[8 * t + 3]);                            \
          u32 y1 = pk2(s[8 * t + 6], s[8 * t + 7]);                            \
          pl32swap(x0, y0);                                                    \
          pl32swap(x1, y1);                                                    \
          union { u32 u[4]; bf16x8 v; } pu;                                    \
          pu.u[0] = x0;                                                        \
          pu.u[1] = x1;                                                        \
          pu.u[2] = y0;                                                        \
          pu.u[3] = y1;                                                        \
          pa[kb * 2 + t] = pu.v;                                               \
        }                                                                      \
      }                                                                        \
      _Pragma("unroll") for (int t = 0; t < 4; ++t)                            \
        lacc = __builtin_amdgcn_mfma_f32_32x32x16_bf16(ones, pa[t], lacc,      \
                                                       0, 0, 0);               \
      _Pragma("unroll") for (int eb = 0; eb < 2; ++eb)                         \
        _Pragma("unroll") for (int t = 0; t < 4; ++t) {                        \
          const bf16x8 vf = *(const bf16x8*)(                                  \
              vs + (eb * 32 + ln) * 64 + (((t * 2 + hi) ^ swz) * 8));          \
          Yt[eb] = __builtin_amdgcn_mfma_f32_32x32x16_bf16(vf, pa[t], Yt[eb],  \
                                                           0, 0, 0);           \
        }                                                                      \
    }                                                                          \
  } while (0)

// one pipeline phase: stage cc+2 into PF, compute cc from CUR, counted wait.
// all conditions are block-uniform (nchunk depends on blockIdx only).
#define PHASE(cc, CUR, PF)                                                     \
  do {                                                                         \
    if ((cc) < nchunk) {                                                       \
      if ((cc) + 2 < nchunk) STAGE((cc) + 2, PF);                              \
      COMPUTE((cc), CUR);                                                      \
      if ((cc) + 2 < nchunk)                                                   \
        asm volatile("s_waitcnt vmcnt(4)" ::: "memory");                       \
      else if ((cc) + 1 < nchunk)                                              \
        asm volatile("s_waitcnt vmcnt(0)" ::: "memory");                       \
      if ((cc) + 1 < nchunk) __builtin_amdgcn_s_barrier();                     \
    }                                                                          \
  } while (0)

  // ---- prologue: chunks 0,1 in flight; wait chunk 0 only
  STAGE(0, 0);
  STAGE(1, 1);
  asm volatile("s_waitcnt vmcnt(4)" ::: "memory");
  __builtin_amdgcn_s_barrier();

  for (int c = 0; c < nchunk; c += 3) {
    PHASE(c, 0, 2);
    PHASE(c + 1, 1, 0);
    PHASE(c + 2, 2, 1);
  }
#undef PHASE
#undef COMPUTE
#undef STAGE

  // ---- epilogue: lane holds q = ln; e = 32*eb + 8*(r>>2) + 4*hi + (r&3)
  const float rl = 1.f / lacc[0];
  const int t_out = t0 + w * 32 + ln;
  u16* yp = y2 + ((size_t)b * T_ + t_out) * C_ + h * E_ + hi * 4;
#pragma unroll
  for (int eb = 0; eb < 2; ++eb)
#pragma unroll
    for (int g = 0; g < 4; ++g) {
      uint2 st;
      st.x = pk2(Yt[eb][4 * g + 0] * rl, Yt[eb][4 * g + 1] * rl);
      st.y = pk2(Yt[eb][4 * g + 2] * rl, Yt[eb][4 * g + 3] * rl);
      *(uint2*)(yp + eb * 32 + g * 8) = st;
    }
}

// ---------------- launch -----------------------------------------------------
extern "C" void kernel_launch(void* const* d_in, const int* in_sizes, int n_in,
                              void* d_out, int out_size, void* d_ws, size_t ws_size,
                              hipStream_t stream) {
  const float* x = (const float*)d_in[0];
  const float* kc = (const float*)d_in[1];
  const float* vc = (const float*)d_in[2];
  const float* Wqkv = (const float*)d_in[3];
  const float* bqkv = (const float*)d_in[4];
  const float* Wproj = (const float*)d_in[5];
  const float* bproj = (const float*)d_in[6];
  float* out = (float*)d_out;

  u16* qh = (u16*)d_ws;                  // 4194304
  u16* y2 = qh + 4194304;                // 4194304
  u16* xb = y2 + 4194304;                // 4194304
  u16* WqT = xb + 4194304;               // 3145728
  u16* WpT = WqT + 3145728;              // 1048576
  u16* Km = WpT + 1048576;               // 20971520 (swizzled layout)
  u16* Vtm = Km + 20971520;              // 20971520 (swizzled layout)

  convert_f32_bf16<<<dim3(2048), 256, 0, stream>>>(x, xb);
  transpose_f32_bf16<<<dim3(48, 16), 256, 0, stream>>>(Wqkv, WqT, 1024, 3072);
  transpose_f32_bf16<<<dim3(16, 16), 256, 0, stream>>>(Wproj, WpT, 1024, 1024);
  prep_kv<<<dim3(128 * 32), 256, 0, stream>>>(kc, vc, Km, Vtm);

  // qkv = x @ Wqkv + bqkv -> qh (xQSCALE), Km[:, L:], Vtm[:, :, L:] (swizzled)
  gemm128<0><<<dim3(24, 32), 256, 0, stream>>>(xb, WqT, bqkv, qh, Km, Vtm, nullptr,
                                               4096, 3072, 1024);

  attn_v10<<<dim3(512), 256, 0, stream>>>(qh, Km, Vtm, y2);

  // out = y @ Wproj + bproj (f32 out): 64x64 tiles, 4 blocks/CU (was 1)
  gemm64<<<dim3(16, 64), 256, 0, stream>>>(y2, WpT, bproj, out, 4096, 1024, 1024);
}

// Round 10
// 313.715 us; speedup vs baseline: 1.0779x; 1.0400x over previous
//
#include <hip/hip_runtime.h>
#include <hip/hip_bf16.h>

typedef unsigned short u16;
typedef unsigned int u32;

constexpr int B_ = 8, T_ = 512, C_ = 1024, H_ = 16, E_ = 64, L_ = 2048;
constexpr int S_ = L_ + T_;  // 2560 merged KV length

typedef __bf16 bf16x8 __attribute__((ext_vector_type(8)));
typedef float f32x4 __attribute__((ext_vector_type(4)));
typedef float f32x16 __attribute__((ext_vector_type(16)));

// 0.125 * log2(e): folds 1/sqrt(E) and the exp->exp2 base change into q
#define QSCALE 0.18033688011112042f

// Km[b,h,s,e] and Vtm[b,h,e,s] are stored PRE-SWIZZLED: within each 128B row
// (8 units of 16B), unit u of row r is stored at u ^ (r & 7). attn stages them
// to LDS linearly via global_load_lds and applies the XOR on the LDS read side.

__device__ inline u16 f2bf(float f) {
  u32 u = __float_as_uint(f);
  u32 r = (u + 0x7fffu + ((u >> 16) & 1u)) >> 16;
  return (u16)r;
}

// packed f32x2 -> bf16x2, hardware RNE single instr
__device__ inline u32 pk2(float a, float b) {
  u32 r;
  asm("v_cvt_pk_bf16_f32 %0, %1, %2" : "=v"(r) : "v"(a), "v"(b));
  return r;
}

// permlane32_swap: a' = concat(a[0:31], b[0:31]); b' = concat(a[32:63], b[32:63])
__device__ inline void pl32swap(u32& a, u32& b) {
  asm("v_permlane32_swap_b32 %0, %1" : "+v"(a), "+v"(b));
}

// raw v_exp_f32 (exp2): skips the OCML range-fixup wrapper. Masked scores
// (-1e30) -> 0 in HW; denormal flush differs only at ~1e-38, negligible vs l.
#if defined(__has_builtin)
#if __has_builtin(__builtin_amdgcn_exp2f)
#define EXP2(x) __builtin_amdgcn_exp2f(x)
#endif
#endif
#ifndef EXP2
__device__ inline float exp2_raw_(float x) {
  float r;
  asm("v_exp_f32 %0, %1" : "=v"(r) : "v"(x));
  return r;
}
#define EXP2(x) exp2_raw_(x)
#endif

// async global->LDS, 16B per lane; lds base must be wave-uniform,
// HW writes lds_base + lane*16
__device__ inline void gload_lds16(const u16* g, u16* l) {
  __builtin_amdgcn_global_load_lds(
      (const __attribute__((address_space(1))) u32*)g,
      (__attribute__((address_space(3))) u32*)l, 16, 0, 0);
}

// ---------------- x (f32) -> bf16, 8 elements/thread -------------------------
__global__ __launch_bounds__(256) void convert_f32_bf16(const float* __restrict__ in,
                                                        u16* __restrict__ out) {
  const int i = blockIdx.x * 256 + threadIdx.x;
  const float4 a0 = ((const float4*)in)[i * 2];
  const float4 a1 = ((const float4*)in)[i * 2 + 1];
  uint4 p;
  p.x = pk2(a0.x, a0.y);
  p.y = pk2(a0.z, a0.w);
  p.z = pk2(a1.x, a1.y);
  p.w = pk2(a1.z, a1.w);
  ((uint4*)out)[i] = p;
}

// ------- transpose + downcast: in f32 (R x Ccols) -> out bf16 (Ccols x R) ----
__global__ __launch_bounds__(256) void transpose_f32_bf16(const float* __restrict__ in,
                                                          u16* __restrict__ out,
                                                          int R, int Ccols) {
  __shared__ u16 tile[64][65];
  const int r0 = blockIdx.y * 64;
  const int c0 = blockIdx.x * 64;
  const int tr = threadIdx.x >> 6;  // 0..3
  const int tc = threadIdx.x & 63;
#pragma unroll
  for (int i = 0; i < 16; ++i)
    tile[tr + i * 4][tc] = f2bf(in[(size_t)(r0 + tr + i * 4) * Ccols + c0 + tc]);
  __syncthreads();
#pragma unroll
  for (int i = 0; i < 16; ++i)
    out[(size_t)(c0 + tr + i * 4) * R + r0 + tc] = tile[tc][tr + i * 4];
}

// ---- prep: f32 KV cache -> swizzled bf16 Km[b,h,s,e], Vtm[b,h,e,s] (s<L) ----
__global__ __launch_bounds__(256) void prep_kv(const float* __restrict__ kc,
                                               const float* __restrict__ vc,
                                               u16* __restrict__ Km,
                                               u16* __restrict__ Vtm) {
  __shared__ u16 vt[64 * 72];
  const int s0 = (blockIdx.x & 31) * 64;
  const int bh = blockIdx.x >> 5;
  const int tid = threadIdx.x;
  const int srow = tid >> 2;
  const int eq = (tid & 3) * 16;

  {
    const float* kp = kc + ((size_t)bh * L_ + s0 + srow) * E_ + eq;
    float kv[16];
    *(float4*)(kv + 0) = *(const float4*)(kp + 0);
    *(float4*)(kv + 4) = *(const float4*)(kp + 4);
    *(float4*)(kv + 8) = *(const float4*)(kp + 8);
    *(float4*)(kv + 12) = *(const float4*)(kp + 12);
    uint4 p0, p1;
    p0.x = pk2(kv[0], kv[1]);
    p0.y = pk2(kv[2], kv[3]);
    p0.z = pk2(kv[4], kv[5]);
    p0.w = pk2(kv[6], kv[7]);
    p1.x = pk2(kv[8], kv[9]);
    p1.y = pk2(kv[10], kv[11]);
    p1.z = pk2(kv[12], kv[13]);
    p1.w = pk2(kv[14], kv[15]);
    // swizzled store: 16B unit u at u ^ (s&7)
    const int sx = (srow & 7) << 3;
    u16* kd = Km + ((size_t)bh * S_ + s0 + srow) * E_;
    *(uint4*)(kd + (eq ^ sx)) = p0;
    *(uint4*)(kd + ((eq + 8) ^ sx)) = p1;
  }
  {
    const float* vp = vc + ((size_t)bh * L_ + s0 + srow) * E_ + eq;
    float vv[16];
    *(float4*)(vv + 0) = *(const float4*)(vp + 0);
    *(float4*)(vv + 4) = *(const float4*)(vp + 4);
    *(float4*)(vv + 8) = *(const float4*)(vp + 8);
    *(float4*)(vv + 12) = *(const float4*)(vp + 12);
    uint4 p0, p1;
    p0.x = pk2(vv[0], vv[1]);
    p0.y = pk2(vv[2], vv[3]);
    p0.z = pk2(vv[4], vv[5]);
    p0.w = pk2(vv[6], vv[7]);
    p1.x = pk2(vv[8], vv[9]);
    p1.y = pk2(vv[10], vv[11]);
    p1.z = pk2(vv[12], vv[13]);
    p1.w = pk2(vv[14], vv[15]);
    *(uint4*)(vt + srow * 72 + eq) = p0;
    *(uint4*)(vt + srow * 72 + eq + 8) = p1;
  }
  __syncthreads();
  {
    const int erow = tid >> 2;
    const int sq = (tid & 3) * 16;
    u16 o[16];
#pragma unroll
    for (int j = 0; j < 16; ++j) o[j] = vt[(sq + j) * 72 + erow];
    // swizzled store: within this 64-key chunk, unit u at u ^ (e&7)
    const int ex = (erow & 7) << 3;
    u16* vd = Vtm + ((size_t)bh * E_ + erow) * S_ + s0;
    *(uint4*)(vd + (sq ^ ex)) = *(uint4*)(o + 0);
    *(uint4*)(vd + ((sq + 8) ^ ex)) = *(uint4*)(o + 8);
  }
}

// --------- m97-style GEMM: C[M,N] = A[M,K] @ BT[N,K]^T + bias[n] -------------
// 128x128 tile, BK=32, global_load_lds staging, 4 waves each 64x64.
// MODE 0: scatter qkv: q (xQSCALE) -> qh[b,h,t,e]; k -> Km[..,L+t,e] swizzled;
//         v -> Vtm[..,e,L+t] swizzled (4 consecutive t merged -> one 8B store)
// MODE 1: f32 row-major store to outf
template <int MODE>
__global__ __launch_bounds__(256) void gemm128(const u16* __restrict__ A,
                                               const u16* __restrict__ BT,
                                               const float* __restrict__ bias,
                                               u16* __restrict__ qh,
                                               u16* __restrict__ Km,
                                               u16* __restrict__ Vtm,
                                               float* __restrict__ outf,
                                               int M, int N, int K) {
  __shared__ __align__(16) u16 As[128 * 32];
  __shared__ __align__(16) u16 Bs[128 * 32];
  const int tid = threadIdx.x;
  const int lane = tid & 63;
  const int w = tid >> 6;
  const int m0 = blockIdx.y * 128;
  const int n0 = blockIdx.x * 128;
  const int wm = (w >> 1) * 64;
  const int wn = (w & 1) * 64;
  const int fm = lane & 15;
  const int fk = (lane >> 4) * 8;

  const int srow = w * 16 + (lane >> 2);
  const int scol = (lane & 3) * 8;
  const u16* Ag = A + (size_t)(m0 + srow) * K + scol;
  const u16* Bg = BT + (size_t)(n0 + srow) * K + scol;
  u16* AsU = As + w * 512;
  u16* BsU = Bs + w * 512;

  f32x4 acc[4][4];
#pragma unroll
  for (int i = 0; i < 4; ++i)
#pragma unroll
    for (int j = 0; j < 4; ++j) acc[i][j] = f32x4{0.f, 0.f, 0.f, 0.f};

  for (int k0 = 0; k0 < K; k0 += 32) {
    gload_lds16(Ag, AsU);
    gload_lds16(Ag + (size_t)64 * K, AsU + 2048);
    gload_lds16(Bg, BsU);
    gload_lds16(Bg + (size_t)64 * K, BsU + 2048);
    Ag += 32;
    Bg += 32;
    __syncthreads();
    bf16x8 af[4], bf[4];
#pragma unroll
    for (int i = 0; i < 4; ++i)
      af[i] = *(const bf16x8*)(As + (wm + i * 16 + fm) * 32 + fk);
#pragma unroll
    for (int j = 0; j < 4; ++j)
      bf[j] = *(const bf16x8*)(Bs + (wn + j * 16 + fm) * 32 + fk);
#pragma unroll
    for (int i = 0; i < 4; ++i)
#pragma unroll
      for (int j = 0; j < 4; ++j)
        acc[i][j] = __builtin_amdgcn_mfma_f32_16x16x32_bf16(af[i], bf[j], acc[i][j], 0, 0, 0);
    __syncthreads();
  }

  const int rbase = (lane >> 4) * 4;
  const int cbase = lane & 15;
#pragma unroll
  for (int i = 0; i < 4; ++i) {
    const int mb = m0 + wm + i * 16 + rbase;  // 4-aligned; block of 4 rows
    const int t = mb & 511;                   // 4-aligned, no 512-crossing
    const int bq = mb >> 9;
#pragma unroll
    for (int j = 0; j < 4; ++j) {
      const int n = n0 + wn + j * 16 + cbase;
      const float bv = bias[n];
      if (MODE == 0) {
        const int seg = n >> 10;  // 0:q 1:k 2:v
        const int c = n & 1023;
        const int e = c & 63;
        const int bhh = bq * H_ + (c >> 6);
        if (seg == 0) {
#pragma unroll
          for (int r = 0; r < 4; ++r)
            qh[((size_t)bhh * T_ + t + r) * E_ + e] =
                f2bf((acc[i][j][r] + bv) * QSCALE);
        } else if (seg == 1) {  // swizzle: e ^ ((s&7)<<3), s = L+t, L%8==0
#pragma unroll
          for (int r = 0; r < 4; ++r)
            Km[((size_t)bhh * S_ + L_ + t + r) * E_ + (e ^ (((t + r) & 7) << 3))] =
                f2bf(acc[i][j][r] + bv);
        } else {
          // V: 4 consecutive t in one Vtm row; swizzle XOR hits bits 3-5 of
          // the s-index only, so the 4 u16 stay contiguous -> one 8B store.
          uint2 pv;
          pv.x = pk2(acc[i][j][0] + bv, acc[i][j][1] + bv);
          pv.y = pk2(acc[i][j][2] + bv, acc[i][j][3] + bv);
          *(uint2*)(Vtm + ((size_t)bhh * E_ + e) * S_ +
                    ((L_ + t) ^ ((e & 7) << 3))) = pv;
        }
      } else {
#pragma unroll
        for (int r = 0; r < 4; ++r)
          outf[(size_t)(mb + r) * N + n] = acc[i][j][r] + bv;
      }
    }
  }
}

// --------- gemm12864: C[M,N] = A[M,K] @ BT[N,K]^T + bias, f32 out ------------
// 128x64 tile, 4 waves each 64x32 (8 MFMAs per barrier round -- 2x gemm64's
// ratio). Proj GEMM grid 16x32 = 512 blocks = 2 blocks/CU. Same BK=32
// accumulation order as gemm64/gemm128 -> bit-identical results.
__global__ __launch_bounds__(256) void gemm12864(const u16* __restrict__ A,
                                                 const u16* __restrict__ BT,
                                                 const float* __restrict__ bias,
                                                 float* __restrict__ outf,
                                                 int M, int N, int K) {
  __shared__ __align__(16) u16 As[128 * 32];
  __shared__ __align__(16) u16 Bs[64 * 32];
  const int tid = threadIdx.x;
  const int lane = tid & 63;
  const int w = tid >> 6;
  const int m0 = blockIdx.y * 128;
  const int n0 = blockIdx.x * 64;
  const int wm = (w >> 1) * 64;
  const int wn = (w & 1) * 32;
  const int fm = lane & 15;
  const int fk = (lane >> 4) * 8;

  // staging: A rows {w*16..+16} and {64+w*16..+16}; B rows {w*16..+16}
  const int srow = w * 16 + (lane >> 2);
  const int scol = (lane & 3) * 8;
  const u16* Ag = A + (size_t)(m0 + srow) * K + scol;
  const u16* Bg = BT + (size_t)(n0 + srow) * K + scol;
  u16* AsU = As + w * 512;
  u16* BsU = Bs + w * 512;

  f32x4 acc[4][2];
#pragma unroll
  for (int i = 0; i < 4; ++i)
#pragma unroll
    for (int j = 0; j < 2; ++j) acc[i][j] = f32x4{0.f, 0.f, 0.f, 0.f};

  for (int k0 = 0; k0 < K; k0 += 32) {
    gload_lds16(Ag, AsU);
    gload_lds16(Ag + (size_t)64 * K, AsU + 2048);
    gload_lds16(Bg, BsU);
    Ag += 32;
    Bg += 32;
    __syncthreads();
    bf16x8 af[4], bf[2];
#pragma unroll
    for (int i = 0; i < 4; ++i)
      af[i] = *(const bf16x8*)(As + (wm + i * 16 + fm) * 32 + fk);
#pragma unroll
    for (int j = 0; j < 2; ++j)
      bf[j] = *(const bf16x8*)(Bs + (wn + j * 16 + fm) * 32 + fk);
#pragma unroll
    for (int i = 0; i < 4; ++i)
#pragma unroll
      for (int j = 0; j < 2; ++j)
        acc[i][j] = __builtin_amdgcn_mfma_f32_16x16x32_bf16(af[i], bf[j], acc[i][j], 0, 0, 0);
    __syncthreads();
  }

  const int rbase = (lane >> 4) * 4;
  const int cbase = lane & 15;
#pragma unroll
  for (int i = 0; i < 4; ++i)
#pragma unroll
    for (int j = 0; j < 2; ++j) {
      const int n = n0 + wn + j * 16 + cbase;
      const float bv = bias[n];
#pragma unroll
      for (int r = 0; r < 4; ++r) {
        const int m = m0 + wm + i * 16 + rbase + r;
        outf[(size_t)m * N + n] = acc[i][j][r] + bv;
      }
    }
}

// ----- MFMA flash attention v11: v10 + raw v_exp_f32 -------------------------
// v10 structure (static 3-buffer rotation, gload_lds + counted vmcnt) with
// exp2f replaced by the raw HW instruction (drops OCML range-fixup VALU ops).
__global__ __launch_bounds__(256, 2) void attn_v11(const u16* __restrict__ qh,
                                                   const u16* __restrict__ Km,
                                                   const u16* __restrict__ Vtm,
                                                   u16* __restrict__ y2) {
  __shared__ __align__(16) u16 Ksf[3 * 4096];
  __shared__ __align__(16) u16 Vtsf[3 * 4096];

  const int tid = threadIdx.x;
  const int lane = tid & 63;
  const int w = tid >> 6;
  const int bh = blockIdx.x & 127;  // same-bh blocks 128 apart
  const int qt = blockIdx.x >> 7;
  const int h = bh & (H_ - 1);
  const int b = bh >> 4;
  const int t0 = qt * 128;

  const int ln = lane & 31;
  const int hi = lane >> 5;
  const int swz = ln & 7;

  // ---- Q fragments (B-operand): lane holds Q[q=ln][e = et*16 + hi*8 + j]
  const u16* qbase = qh + ((size_t)bh * T_ + t0 + w * 32 + ln) * E_;
  bf16x8 qf[4];
#pragma unroll
  for (int et = 0; et < 4; ++et)
    qf[et] = *(const bf16x8*)(qbase + et * 16 + hi * 8);

  // ---- staging: wave w stages rows [w*16, w*16+16) of each 64-row tile.
  const int l8 = lane >> 3;
  const int u8 = lane & 7;
  const u16* kgl = Km + ((size_t)bh * S_ + w * 16 + l8) * E_ + u8 * 8;
  const u16* vgl = Vtm + ((size_t)bh * E_ + w * 16 + l8) * S_ + u8 * 8;
  const int kdst = w * 1024;  // u16 units; +512 = +8 rows

#define STAGE(cc, bi)                                                       \
  do {                                                                      \
    gload_lds16(kgl + (size_t)(cc) * 64 * E_, Ksf + (bi) * 4096 + kdst);    \
    gload_lds16(kgl + ((size_t)(cc) * 64 + 8) * E_,                         \
                Ksf + (bi) * 4096 + kdst + 512);                            \
    gload_lds16(vgl + (cc) * 64, Vtsf + (bi) * 4096 + kdst);                \
    gload_lds16(vgl + (size_t)8 * S_ + (cc) * 64,                           \
                Vtsf + (bi) * 4096 + kdst + 512);                           \
  } while (0)

  f32x16 Yt[2], lacc, zero16;
#pragma unroll
  for (int i = 0; i < 16; ++i) {
    Yt[0][i] = 0.f;
    Yt[1][i] = 0.f;
    lacc[i] = 0.f;
    zero16[i] = 0.f;
  }

  const bf16x8 ones = {(__bf16)1.f, (__bf16)1.f, (__bf16)1.f, (__bf16)1.f,
                       (__bf16)1.f, (__bf16)1.f, (__bf16)1.f, (__bf16)1.f};

  const int qmin_w = L_ + t0 + w * 32;
  const int qpos = qmin_w + ln;
  const int nchunk = (L_ + t0 + 128) >> 6;  // 34..40

// compute chunk cc from static buffer BI
#define COMPUTE(cc, BI)                                                        \
  do {                                                                         \
    if (((cc) << 6) <= qmin_w + 31) {                                          \
      const int sbase = (cc) << 6;                                             \
      const u16* ks = Ksf + (BI) * 4096;                                       \
      const u16* vs = Vtsf + (BI) * 4096;                                      \
      bf16x8 pa[4];                                                            \
      _Pragma("unroll") for (int kb = 0; kb < 2; ++kb) {                       \
        f32x16 s;                                                              \
        _Pragma("unroll") for (int et = 0; et < 4; ++et) {                     \
          const bf16x8 kf = *(const bf16x8*)(                                  \
              ks + (kb * 32 + ln) * 64 + (((et * 2 + hi) ^ swz) * 8));         \
          s = __builtin_amdgcn_mfma_f32_32x32x16_bf16(kf, qf[et],              \
                                                      et == 0 ? zero16 : s,    \
                                                      0, 0, 0);                \
        }                                                                      \
        if (sbase + 63 > qmin_w) {                                             \
          const int mb = sbase + kb * 32 + hi * 4;                             \
          _Pragma("unroll") for (int rr = 0; rr < 16; ++rr) {                  \
            const int keypos = mb + (rr & 3) + 8 * (rr >> 2);                  \
            if (keypos > qpos) s[rr] = -1e30f;                                 \
          }                                                                    \
        }                                                                      \
        _Pragma("unroll") for (int rr = 0; rr < 16; ++rr) s[rr] = EXP2(s[rr]); \
        _Pragma("unroll") for (int t = 0; t < 2; ++t) {                        \
          u32 x0 = pk2(s[8 * t + 0], s[8 * t + 1]);                            \
          u32 y0 = pk2(s[8 * t + 4], s[8 * t + 5]);                            \
          u32 x1 = pk2(s[8 * t + 2], s[8 * t + 3]);                            \
          u32 y1 = pk2(s[8 * t + 6], s[8 * t + 7]);                            \
          pl32swap(x0, y0);                                                    \
          pl32swap(x1, y1);                                                    \
          union { u32 u[4]; bf16x8 v; } pu;                                    \
          pu.u[0] = x0;                                                        \
          pu.u[1] = x1;                                                        \
          pu.u[2] = y0;                                                        \
          pu.u[3] = y1;                                                        \
          pa[kb * 2 + t] = pu.v;                                               \
        }                                                                      \
      }                                                                        \
      _Pragma("unroll") for (int t = 0; t < 4; ++t)                            \
        lacc = __builtin_amdgcn_mfma_f32_32x32x16_bf16(ones, pa[t], lacc,      \
                                                       0, 0, 0);               \
      _Pragma("unroll") for (int eb = 0; eb < 2; ++eb)                         \
        _Pragma("unroll") for (int t = 0; t < 4; ++t) {                        \
          const bf16x8 vf = *(const bf16x8*)(                                  \
              vs + (eb * 32 + ln) * 64 + (((t * 2 + hi) ^ swz) * 8));          \
          Yt[eb] = __builtin_amdgcn_mfma_f32_32x32x16_bf16(vf, pa[t], Yt[eb],  \
                                                           0, 0, 0);           \
        }                                                                      \
    }                                                                          \
  } while (0)

// one pipeline phase: stage cc+2 into PF, compute cc from CUR, counted wait.
// all conditions are block-uniform (nchunk depends on blockIdx only).
#define PHASE(cc, CUR, PF)                                                     \
  do {                                                                         \
    if ((cc) < nchunk) {                                                       \
      if ((cc) + 2 < nchunk) STAGE((cc) + 2, PF);                              \
      COMPUTE((cc), CUR);                                                      \
      if ((cc) + 2 < nchunk)                                                   \
        asm volatile("s_waitcnt vmcnt(4)" ::: "memory");                       \
      else if ((cc) + 1 < nchunk)                                              \
        asm volatile("s_waitcnt vmcnt(0)" ::: "memory");                       \
      if ((cc) + 1 < nchunk) __builtin_amdgcn_s_barrier();                     \
    }                                                                          \
  } while (0)

  // ---- prologue: chunks 0,1 in flight; wait chunk 0 only
  STAGE(0, 0);
  STAGE(1, 1);
  asm volatile("s_waitcnt vmcnt(4)" ::: "memory");
  __builtin_amdgcn_s_barrier();

  for (int c = 0; c < nchunk; c += 3) {
    PHASE(c, 0, 2);
    PHASE(c + 1, 1, 0);
    PHASE(c + 2, 2, 1);
  }
#undef PHASE
#undef COMPUTE
#undef STAGE

  // ---- epilogue: lane holds q = ln; e = 32*eb + 8*(r>>2) + 4*hi + (r&3)
  const float rl = 1.f / lacc[0];
  const int t_out = t0 + w * 32 + ln;
  u16* yp = y2 + ((size_t)b * T_ + t_out) * C_ + h * E_ + hi * 4;
#pragma unroll
  for (int eb = 0; eb < 2; ++eb)
#pragma unroll
    for (int g = 0; g < 4; ++g) {
      uint2 st;
      st.x = pk2(Yt[eb][4 * g + 0] * rl, Yt[eb][4 * g + 1] * rl);
      st.y = pk2(Yt[eb][4 * g + 2] * rl, Yt[eb][4 * g + 3] * rl);
      *(uint2*)(yp + eb * 32 + g * 8) = st;
    }
}

// ---------------- launch -----------------------------------------------------
extern "C" void kernel_launch(void* const* d_in, const int* in_sizes, int n_in,
                              void* d_out, int out_size, void* d_ws, size_t ws_size,
                              hipStream_t stream) {
  const float* x = (const float*)d_in[0];
  const float* kc = (const float*)d_in[1];
  const float* vc = (const float*)d_in[2];
  const float* Wqkv = (const float*)d_in[3];
  const float* bqkv = (const float*)d_in[4];
  const float* Wproj = (const float*)d_in[5];
  const float* bproj = (const float*)d_in[6];
  float* out = (float*)d_out;

  u16* qh = (u16*)d_ws;                  // 4194304
  u16* y2 = qh + 4194304;                // 4194304
  u16* xb = y2 + 4194304;                // 4194304
  u16* WqT = xb + 4194304;               // 3145728
  u16* WpT = WqT + 3145728;              // 1048576
  u16* Km = WpT + 1048576;               // 20971520 (swizzled layout)
  u16* Vtm = Km + 20971520;              // 20971520 (swizzled layout)

  convert_f32_bf16<<<dim3(2048), 256, 0, stream>>>(x, xb);
  transpose_f32_bf16<<<dim3(48, 16), 256, 0, stream>>>(Wqkv, WqT, 1024, 3072);
  transpose_f32_bf16<<<dim3(16, 16), 256, 0, stream>>>(Wproj, WpT, 1024, 1024);
  prep_kv<<<dim3(128 * 32), 256, 0, stream>>>(kc, vc, Km, Vtm);

  // qkv = x @ Wqkv + bqkv -> qh (xQSCALE), Km[:, L:], Vtm[:, :, L:] (swizzled)
  gemm128<0><<<dim3(24, 32), 256, 0, stream>>>(xb, WqT, bqkv, qh, Km, Vtm, nullptr,
                                               4096, 3072, 1024);

  attn_v11<<<dim3(512), 256, 0, stream>>>(qh, Km, Vtm, y2);

  // out = y @ Wproj + bproj (f32): 128x64 tiles, 2 blocks/CU, 8 MFMA/round
  gemm12864<<<dim3(16, 32), 256, 0, stream>>>(y2, WpT, bproj, out, 4096, 1024, 1024);
}